// Round 18
// baseline (86.515 us; speedup 1.0000x reference)
//
#include <hip/hip_runtime.h>
#include <stdint.h>

#define BB 8
#define NN 2048
#define EE 2048
#define DD 128
#define RBP 132
#define NTHREADS 256
#define WMAT_U32 8192   // one 128x128 bf16 matrix, u32-packed (k-pairs)
#define SCANGB 4096     // scan+gather blocks in K2 (first in grid)
#define LCAP 64         // max nonzeros per node row (mean 20.5)

typedef __attribute__((ext_vector_type(8))) short bf16x8;
typedef __attribute__((ext_vector_type(4))) float f32x4;

__device__ inline unsigned bf16rne(float f) {
    unsigned u = __float_as_uint(f);
    return (u + 0x7fffu + ((u >> 16) & 1u)) >> 16;
}
__device__ inline float bf16lo(unsigned u) { return __uint_as_float(u << 16); }
__device__ inline float bf16hi(unsigned u) { return __uint_as_float(u & 0xffff0000u); }

// XOR-swizzle byte offset inside a [rows][256B] bf16 tile (row = byte>>8)
#define SWZ(b) ((b) ^ ((((b) >> 8) & 7) << 4))

struct __align__(16) SmemK1 {      // 32-row MLP1 tiles
    float rowbuf[32][RBP];
    unsigned h[32 * 64];
    int rmask[32];
    int ords[32];
};

struct __align__(16) SmemK3 {      // 16-row tiles
    float rowbuf[16][RBP];
    unsigned h[16 * 64];
    int rmask[16];
};

// ================== 32-row MLP1 helpers ==================
__device__ inline void load_rows32(SmemK1& s, const float* __restrict__ src) {
    int t = threadIdx.x;
    for (int idx = t; idx < 32 * 32; idx += NTHREADS) {
        int r = idx >> 5, c4 = (idx & 31) * 4;
        float4 v = *(const float4*)&src[r * DD + c4];   // unconditional
        *(float4*)&s.rowbuf[r][c4] = v;
    }
    __syncthreads();
    for (int idx = t; idx < 32 * 32; idx += NTHREADS) {
        int r = idx >> 5, c4 = (idx & 31) * 4;
        if (s.rmask[r] == 0) *(float4*)&s.rowbuf[r][c4] = make_float4(0.f, 0.f, 0.f, 0.f);
    }
    __syncthreads();
}

__device__ inline void ln32(SmemK1& s, const float* __restrict__ gw,
                            const float* __restrict__ bw,
                            const float* __restrict__ pe_base, bool per_row_pe) {
    int t = threadIdx.x;
    int gr = t >> 3, g = t & 7;
    int base = g * 16;
    float x[16];
    float4* xp = (float4*)x;
    xp[0] = *(const float4*)&s.rowbuf[gr][base + 0];
    xp[1] = *(const float4*)&s.rowbuf[gr][base + 4];
    xp[2] = *(const float4*)&s.rowbuf[gr][base + 8];
    xp[3] = *(const float4*)&s.rowbuf[gr][base + 12];
    float s1 = 0.f, s2 = 0.f;
    #pragma unroll
    for (int i = 0; i < 16; i++) { s1 += x[i]; s2 += x[i] * x[i]; }
    #pragma unroll
    for (int off = 1; off < 8; off <<= 1) {
        s1 += __shfl_xor(s1, off, 64);
        s2 += __shfl_xor(s2, off, 64);
    }
    float mu = s1 * (1.f / 128.f);
    float var = s2 * (1.f / 128.f) - mu * mu;
    float rstd = rsqrtf(var + 1e-5f);
    const float* pe = nullptr;
    if (pe_base) pe = per_row_pe ? (pe_base + (size_t)s.ords[gr] * DD) : pe_base;
    unsigned p[8];
    #pragma unroll
    for (int j = 0; j < 8; j++) {
        int k0 = base + 2 * j;
        float v0 = (x[2 * j] - mu) * rstd * gw[k0] + bw[k0];
        float v1 = (x[2 * j + 1] - mu) * rstd * gw[k0 + 1] + bw[k0 + 1];
        if (pe) { v0 += pe[k0]; v1 += pe[k0 + 1]; }
        p[j] = bf16rne(v0) | (bf16rne(v1) << 16);
    }
    char* hb = (char*)s.h;
    int byte0 = gr * 256 + g * 32;
    uint4 lo = make_uint4(p[0], p[1], p[2], p[3]);
    uint4 hi = make_uint4(p[4], p[5], p[6], p[7]);
    *(uint4*)(hb + SWZ(byte0)) = lo;
    *(uint4*)(hb + SWZ(byte0 + 16)) = hi;
    __syncthreads();
}

template <bool TO_H>
__device__ inline void mm32_f32w(SmemK1& s, const float* __restrict__ Wf,
                                 const float* __restrict__ bias) {
    int t = threadIdx.x;
    int w = t >> 6, l = t & 63;
    int lm = l & 15, lk = l >> 4;
    bf16x8 bfr[2][4];
    #pragma unroll
    for (int nbl = 0; nbl < 2; nbl++) {
        int n = w * 32 + nbl * 16 + lm;
        #pragma unroll
        for (int kb = 0; kb < 4; kb++) {
            int k0 = kb * 32 + lk * 8;
            unsigned pk[4];
            #pragma unroll
            for (int jp = 0; jp < 4; jp++) {
                float a = Wf[(size_t)(k0 + 2 * jp) * DD + n];
                float b = Wf[(size_t)(k0 + 2 * jp + 1) * DD + n];
                pk[jp] = bf16rne(a) | (bf16rne(b) << 16);
            }
            uint4 u = make_uint4(pk[0], pk[1], pk[2], pk[3]);
            bfr[nbl][kb] = *(bf16x8*)&u;
        }
    }
    const char* hb = (const char*)s.h;
    bf16x8 afr[2][4];
    #pragma unroll
    for (int mb = 0; mb < 2; mb++) {
        int row = mb * 16 + lm;
        #pragma unroll
        for (int kb = 0; kb < 4; kb++)
            afr[mb][kb] = *(const bf16x8*)(hb + SWZ(row * 256 + kb * 64 + lk * 16));
    }
    f32x4 acc[2][2];
    #pragma unroll
    for (int mb = 0; mb < 2; mb++)
        #pragma unroll
        for (int nbl = 0; nbl < 2; nbl++)
            acc[mb][nbl] = (f32x4){0.f, 0.f, 0.f, 0.f};
    #pragma unroll
    for (int kb = 0; kb < 4; kb++)
        #pragma unroll
        for (int mb = 0; mb < 2; mb++)
            #pragma unroll
            for (int nbl = 0; nbl < 2; nbl++)
                acc[mb][nbl] = __builtin_amdgcn_mfma_f32_16x16x32_bf16(
                    afr[mb][kb], bfr[nbl][kb], acc[mb][nbl], 0, 0, 0);
    float bcol0 = bias[w * 32 + lm];
    float bcol1 = bias[w * 32 + 16 + lm];
    __syncthreads();
    if (TO_H) {
        char* hw = (char*)s.h;
        #pragma unroll
        for (int mb = 0; mb < 2; mb++)
            #pragma unroll
            for (int nbl = 0; nbl < 2; nbl++) {
                int col = w * 32 + nbl * 16 + lm;
                float bc = nbl ? bcol1 : bcol0;
                #pragma unroll
                for (int j = 0; j < 4; j++) {
                    int row = mb * 16 + lk * 4 + j;
                    float v = fmaxf(acc[mb][nbl][j] + bc, 0.f);
                    *(unsigned short*)(hw + SWZ(row * 256 + col * 2)) =
                        (unsigned short)bf16rne(v);
                }
            }
    } else {
        #pragma unroll
        for (int mb = 0; mb < 2; mb++)
            #pragma unroll
            for (int nbl = 0; nbl < 2; nbl++) {
                int col = w * 32 + nbl * 16 + lm;
                float bc = nbl ? bcol1 : bcol0;
                #pragma unroll
                for (int j = 0; j < 4; j++) {
                    int row = mb * 16 + lk * 4 + j;
                    s.rowbuf[row][col] += acc[mb][nbl][j] + bc;
                }
            }
    }
    __syncthreads();
}

// ---- node/edge MLP1 tile body (shared by K1 edge blocks and K2 node blocks) ----
__device__ inline void mlp1_tile(SmemK1& s, bool isEdge, int rowbase,
                                 const float* __restrict__ xsrc,
                                 const int* __restrict__ mask,
                                 const int* __restrict__ eord,
                                 const float* __restrict__ pe1,
                                 const float* __restrict__ n1g, const float* __restrict__ n1b,
                                 const float* __restrict__ W11, const float* __restrict__ b11,
                                 const float* __restrict__ W12, const float* __restrict__ b12,
                                 unsigned* __restrict__ e2pk, float* __restrict__ v2out) {
    int t = threadIdx.x;
    if (t < 32) {
        s.rmask[t] = mask[rowbase + t];
        if (isEdge) {
            int o = eord[rowbase + t];
            s.ords[t] = o < 0 ? 0 : (o > 8 ? 8 : o);
        }
    }
    __syncthreads();
    load_rows32(s, xsrc + (size_t)rowbase * DD);
    ln32(s, n1g, n1b, isEdge ? pe1 : (pe1 + DD), isEdge);
    mm32_f32w<true>(s, W11, b11);
    mm32_f32w<false>(s, W12, b12);
    if (isEdge) {
        unsigned* dst = e2pk + (size_t)rowbase * (DD / 2);
        for (int idx = t; idx < 32 * 16; idx += NTHREADS) {
            int r = idx >> 4, q = idx & 15;
            uint4 o = make_uint4(0u, 0u, 0u, 0u);
            if (s.rmask[r] != 0) {
                const float* rp = &s.rowbuf[r][q * 8];
                o.x = bf16rne(rp[0]) | (bf16rne(rp[1]) << 16);
                o.y = bf16rne(rp[2]) | (bf16rne(rp[3]) << 16);
                o.z = bf16rne(rp[4]) | (bf16rne(rp[5]) << 16);
                o.w = bf16rne(rp[6]) | (bf16rne(rp[7]) << 16);
            }
            *(uint4*)&dst[r * 64 + q * 4] = o;
        }
    } else {
        for (int idx = t; idx < 32 * 32; idx += NTHREADS) {
            int r = idx >> 5, c4 = (idx & 31) * 4;
            float4 v = make_float4(0.f, 0.f, 0.f, 0.f);
            if (s.rmask[r] != 0) v = *(const float4*)&s.rowbuf[r][c4];
            *(float4*)&v2out[(size_t)(rowbase + r) * DD + c4] = v;
        }
    }
}

// ---- K1: edge MLP1 only (512 blocks) + WT pack ----
__global__ __launch_bounds__(NTHREADS) void k1_kernel(
    const float* __restrict__ x_e, const int* __restrict__ emask,
    const int* __restrict__ eord, const float* __restrict__ pe1,
    const float* __restrict__ n1g, const float* __restrict__ n1b,
    const float* __restrict__ W11, const float* __restrict__ b11,
    const float* __restrict__ W12, const float* __restrict__ b12,
    const float* __restrict__ W21, const float* __restrict__ W22,
    const float* __restrict__ W31, const float* __restrict__ W32,
    unsigned* __restrict__ WT, unsigned* __restrict__ e2pk) {
    __shared__ SmemK1 s;
    int bid = blockIdx.x;
    int t = threadIdx.x;
    // pack W21/W22/W31/W32 -> WT (first 128 blocks, 1 u32/thread)
    int gtid = bid * NTHREADS + t;
    if (gtid < 4 * WMAT_U32) {
        int mat = gtid >> 13;
        int idx = gtid & (WMAT_U32 - 1);
        int n = idx >> 6, j = idx & 63;
        const float* W = mat == 0 ? W21 : mat == 1 ? W22 : mat == 2 ? W31 : W32;
        float a = W[(2 * j) * DD + n];
        float b = W[(2 * j + 1) * DD + n];
        WT[gtid] = bf16rne(a) | (bf16rne(b) << 16);
    }
    int bb = bid & 7;                            // batch -> XCD clustering
    int r0 = (bid >> 3) * 32;
    int rowbase = bb * EE + r0;
    mlp1_tile(s, true, rowbase, x_e, emask, eord, pe1,
              n1g, n1b, W11, b11, W12, b12, e2pk, nullptr);
}

// ---- K2: scan+gather (blocks [0,4096)) + node MLP1 ([4096,4608)) ----
__global__ __launch_bounds__(NTHREADS) void k2_kernel(
    const float* __restrict__ inc, const int* __restrict__ nmask,
    const float* __restrict__ sn, const unsigned* __restrict__ e2pk,
    float* __restrict__ agg,
    const float* __restrict__ x_v, const float* __restrict__ pe1,
    const float* __restrict__ n1g, const float* __restrict__ n1b,
    const float* __restrict__ W11, const float* __restrict__ b11,
    const float* __restrict__ W12, const float* __restrict__ b12,
    float* __restrict__ v2out) {
    __shared__ SmemK1 s;                          // scan path uses only s.h as scratch
    int bid = blockIdx.x;
    int t = threadIdx.x;
    if (bid < SCANGB) {
        int wib = t >> 6, l = t & 63;
        int grow = bid * 4 + wib;
        if (nmask[grow] == 0) return;             // K3 never consumes masked agg
        unsigned long long lmlt = (1ull << l) - 1ull;
        const float4* ir = (const float4*)(inc + (size_t)grow * EE);
        float4 v[8];
        #pragma unroll
        for (int i = 0; i < 8; i++) v[i] = ir[l + 64 * i];   // 8 KB/wave in flight
        unsigned* sc = &s.h[wib * 64];
        int total = 0;
        #pragma unroll
        for (int i = 0; i < 8; i++) {
            #pragma unroll
            for (int c = 0; c < 4; c++) {
                float a = (c == 0) ? v[i].x : (c == 1) ? v[i].y : (c == 2) ? v[i].z : v[i].w;
                bool nz = (a != 0.f);
                unsigned long long msk = __ballot(nz);
                if (nz) {
                    int p = total + __popcll(msk & lmlt);
                    if (p < LCAP) sc[p] = (unsigned)((l + 64 * i) * 4 + c);
                }
                total += __popcll(msk);
            }
        }
        if (total > LCAP) total = LCAP;
        asm volatile("s_waitcnt lgkmcnt(0)" ::: "memory");   // wave-local LDS ordering
        unsigned pk = (l < total) ? sc[l] : 0u;
        const unsigned* e2b = e2pk + (size_t)(grow >> 11) * (EE * (DD / 2));
        float ax = 0.f, ay = 0.f;
        for (int j0 = 0; j0 < total; j0 += 8) {
            int nn = total - j0;
            unsigned uv[8];
            #pragma unroll
            for (int u = 0; u < 8; u++) {
                unsigned e = __shfl(pk, j0 + u, 64);
                uv[u] = (u < nn) ? e2b[(size_t)e * 64 + l] : 0u;
            }
            #pragma unroll
            for (int u = 0; u < 8; u++) { ax += bf16lo(uv[u]); ay += bf16hi(uv[u]); }
        }
        float inv = 1.f / (1.f + sn[grow]);
        *(float2*)&agg[(size_t)grow * DD + 2 * l] = make_float2(ax * inv, ay * inv);
        return;
    }
    // node MLP1 tile (independent of edges -> hidden under the scan)
    int mb = bid - SCANGB;
    int bb = mb & 7;                              // batch -> XCD clustering
    int r0 = (mb >> 3) * 32;
    int rowbase = bb * NN + r0;
    mlp1_tile(s, false, rowbase, x_v, nmask, nullptr, pe1,
              n1g, n1b, W11, b11, W12, b12, nullptr, v2out);
}

// ================== K3 16-row helpers ==================
__device__ inline void ln16(SmemK3& s, const float* __restrict__ gw,
                            const float* __restrict__ bw,
                            const float* __restrict__ pe) {
    int t = threadIdx.x;
    int gr = t >> 4, g = t & 15;
    int base = g * 8;
    float x[8];
    float4* xp = (float4*)x;
    xp[0] = *(const float4*)&s.rowbuf[gr][base + 0];
    xp[1] = *(const float4*)&s.rowbuf[gr][base + 4];
    float s1 = 0.f, s2 = 0.f;
    #pragma unroll
    for (int i = 0; i < 8; i++) { s1 += x[i]; s2 += x[i] * x[i]; }
    #pragma unroll
    for (int off = 1; off < 16; off <<= 1) {
        s1 += __shfl_xor(s1, off, 64);
        s2 += __shfl_xor(s2, off, 64);
    }
    float mu = s1 * (1.f / 128.f);
    float var = s2 * (1.f / 128.f) - mu * mu;
    float rstd = rsqrtf(var + 1e-5f);
    unsigned p[4];
    #pragma unroll
    for (int j = 0; j < 4; j++) {
        int k0 = base + 2 * j;
        float v0 = (x[2 * j] - mu) * rstd * gw[k0] + bw[k0];
        float v1 = (x[2 * j + 1] - mu) * rstd * gw[k0 + 1] + bw[k0 + 1];
        if (pe) { v0 += pe[k0]; v1 += pe[k0 + 1]; }
        p[j] = bf16rne(v0) | (bf16rne(v1) << 16);
    }
    char* hb = (char*)s.h;
    uint4 q = make_uint4(p[0], p[1], p[2], p[3]);
    *(uint4*)(hb + SWZ(gr * 256 + g * 16)) = q;
    __syncthreads();
}

template <bool TO_H>
__device__ inline void mm16(SmemK3& s, const unsigned* __restrict__ WT,
                            const float* __restrict__ bias) {
    int t = threadIdx.x;
    int w = t >> 6, l = t & 63;
    int lm = l & 15, lk = l >> 4;
    bf16x8 bfr[2][4];
    const uint4* wt4 = (const uint4*)WT;
    #pragma unroll
    for (int nbl = 0; nbl < 2; nbl++) {
        int n = w * 32 + nbl * 16 + lm;
        #pragma unroll
        for (int kb = 0; kb < 4; kb++) {
            uint4 u = wt4[n * 16 + kb * 4 + lk];
            bfr[nbl][kb] = *(bf16x8*)&u;
        }
    }
    const char* hb = (const char*)s.h;
    bf16x8 afr[4];
    #pragma unroll
    for (int kb = 0; kb < 4; kb++)
        afr[kb] = *(const bf16x8*)(hb + SWZ(lm * 256 + kb * 64 + lk * 16));
    f32x4 acc[2];
    acc[0] = (f32x4){0.f, 0.f, 0.f, 0.f};
    acc[1] = (f32x4){0.f, 0.f, 0.f, 0.f};
    #pragma unroll
    for (int kb = 0; kb < 4; kb++)
        #pragma unroll
        for (int nbl = 0; nbl < 2; nbl++)
            acc[nbl] = __builtin_amdgcn_mfma_f32_16x16x32_bf16(
                afr[kb], bfr[nbl][kb], acc[nbl], 0, 0, 0);
    float bcol0 = bias[w * 32 + lm];
    float bcol1 = bias[w * 32 + 16 + lm];
    __syncthreads();
    if (TO_H) {
        char* hw = (char*)s.h;
        #pragma unroll
        for (int nbl = 0; nbl < 2; nbl++) {
            int col = w * 32 + nbl * 16 + lm;
            float bc = nbl ? bcol1 : bcol0;
            #pragma unroll
            for (int j = 0; j < 4; j++) {
                int row = lk * 4 + j;
                float v = fmaxf(acc[nbl][j] + bc, 0.f);
                *(unsigned short*)(hw + SWZ(row * 256 + col * 2)) =
                    (unsigned short)bf16rne(v);
            }
        }
    } else {
        #pragma unroll
        for (int nbl = 0; nbl < 2; nbl++) {
            int col = w * 32 + nbl * 16 + lm;
            float bc = nbl ? bcol1 : bcol0;
            #pragma unroll
            for (int j = 0; j < 4; j++) {
                int row = lk * 4 + j;
                s.rowbuf[row][col] += acc[nbl][j] + bc;
            }
        }
    }
    __syncthreads();
}

// ---- K3: x1 = v2 + agg; MLP2 + MLP3; streaming 16-row tiles ----
__global__ __launch_bounds__(NTHREADS) void k3_kernel(
    const float* __restrict__ v2, const int* __restrict__ nmask,
    const float* __restrict__ agg,
    const float* __restrict__ pe2, const float* __restrict__ biasb,
    const float* __restrict__ n2g, const float* __restrict__ n2b,
    const float* __restrict__ n3g, const float* __restrict__ n3b,
    const unsigned* __restrict__ WT,
    const float* __restrict__ b21, const float* __restrict__ b22,
    const float* __restrict__ b31, const float* __restrict__ b32,
    float* __restrict__ out) {
    __shared__ SmemK3 s;
    int bid = blockIdx.x;
    int bb = bid & 7;                            // batch -> XCD clustering
    int n0 = (bid >> 3) * 16;
    int row0 = bb * NN + n0;
    int t = threadIdx.x;
    if (t < 16) s.rmask[t] = nmask[row0 + t];
    for (int idx = t; idx < 16 * 32; idx += NTHREADS) {   // v2 (masked rows zeroed by K2)
        int r = idx >> 5, c4 = (idx & 31) * 4;
        float4 v = *(const float4*)&v2[(size_t)(row0 + r) * DD + c4];
        *(float4*)&s.rowbuf[r][c4] = v;
    }
    __syncthreads();
    for (int idx = t; idx < 16 * 32; idx += NTHREADS) {
        int r = idx >> 5, c4 = (idx & 31) * 4;
        if (s.rmask[r] != 0) {
            float4 a = *(const float4*)&agg[(size_t)(row0 + r) * DD + c4];
            float4* rb = (float4*)&s.rowbuf[r][c4];
            float4 cur = *rb;
            cur.x += a.x; cur.y += a.y; cur.z += a.z; cur.w += a.w;
            *rb = cur;
        }
    }
    __syncthreads();
    ln16(s, n2g, n2b, pe2 + DD);
    mm16<true>(s, WT + 0 * WMAT_U32, b21);
    mm16<false>(s, WT + 1 * WMAT_U32, b22);
    ln16(s, n3g, n3b, nullptr);
    mm16<true>(s, WT + 2 * WMAT_U32, b31);
    mm16<false>(s, WT + 3 * WMAT_U32, b32);
    for (int idx = t; idx < 16 * 32; idx += NTHREADS) {
        int r = idx >> 5, c4 = (idx & 31) * 4;
        float4 v = make_float4(0.f, 0.f, 0.f, 0.f);
        if (s.rmask[r] != 0) {
            v = *(const float4*)&s.rowbuf[r][c4];
            float4 bbv = *(const float4*)&biasb[c4];
            v.x += bbv.x; v.y += bbv.y; v.z += bbv.z; v.w += bbv.w;
        }
        *(float4*)&out[(size_t)(row0 + r) * DD + c4] = v;
    }
}

extern "C" void kernel_launch(void* const* d_in, const int* in_sizes, int n_in,
                              void* d_out, int out_size, void* d_ws, size_t ws_size,
                              hipStream_t stream) {
    const float* x_v   = (const float*)d_in[0];
    const float* x_e   = (const float*)d_in[1];
    const float* inc   = (const float*)d_in[2];
    const float* sn    = (const float*)d_in[3];
    const int*   eord  = (const int*)d_in[4];
    const int*   nmask = (const int*)d_in[5];
    const int*   emask = (const int*)d_in[6];
    const float* pe1   = (const float*)d_in[7];
    const float* pe2   = (const float*)d_in[8];
    const float* biasb = (const float*)d_in[9];
    const float* W11   = (const float*)d_in[10];
    const float* b11   = (const float*)d_in[11];
    const float* W12   = (const float*)d_in[12];
    const float* b12   = (const float*)d_in[13];
    const float* W21   = (const float*)d_in[14];
    const float* b21   = (const float*)d_in[15];
    const float* W22   = (const float*)d_in[16];
    const float* b22   = (const float*)d_in[17];
    const float* W31   = (const float*)d_in[18];
    const float* b31   = (const float*)d_in[19];
    const float* W32   = (const float*)d_in[20];
    const float* b32   = (const float*)d_in[21];
    const float* n1g   = (const float*)d_in[22];
    const float* n1b   = (const float*)d_in[23];
    const float* n2g   = (const float*)d_in[24];
    const float* n2b   = (const float*)d_in[25];
    const float* n3g   = (const float*)d_in[26];
    const float* n3b   = (const float*)d_in[27];

    // d_ws: e2pk bf16 [4 MB] | WT bf16 [128 KB] | agg fp32 [8.4 MB]
    unsigned* e2pk = (unsigned*)d_ws;
    unsigned* WT   = e2pk + (size_t)BB * EE * (DD / 2);
    float*    agg  = (float*)(WT + 4 * WMAT_U32);
    float*    out  = (float*)d_out;   // K2 stages v2 here; K3 overwrites with final

    dim3 blk(NTHREADS);
    k1_kernel<<<dim3(BB * EE / 32), blk, 0, stream>>>(
        x_e, emask, eord, pe1, n1g, n1b, W11, b11, W12, b12,
        W21, W22, W31, W32, WT, e2pk);
    k2_kernel<<<dim3(SCANGB + BB * NN / 32), blk, 0, stream>>>(
        inc, nmask, sn, e2pk, agg,
        x_v, pe1, n1g, n1b, W11, b11, W12, b12, out);
    k3_kernel<<<dim3(BB * NN / 16), blk, 0, stream>>>(
        out, nmask, agg, pe2, biasb,
        n2g, n2b, n3g, n3b,
        WT, b21, b22, b31, b32, out);
}

// Round 19
// 61.909 us; speedup vs baseline: 1.3975x; 1.3975x over previous
//
#include <hip/hip_runtime.h>
#include <stdint.h>

#define BB 8
#define NN 2048
#define EE 2048
#define DD 128
#define RBP 132
#define NTHREADS 256
#define WMAT_U32 8192
#define SCANB 4096
#define MLPB 1024
#define LCAP 64

typedef __attribute__((ext_vector_type(8))) short bf16x8;
typedef __attribute__((ext_vector_type(4))) float f32x4;

__device__ inline unsigned bf16rne(float f) {
    unsigned u = __float_as_uint(f);
    return (u + 0x7fffu + ((u >> 16) & 1u)) >> 16;
}
__device__ inline float bf16lo(unsigned u) { return __uint_as_float(u << 16); }
__device__ inline float bf16hi(unsigned u) { return __uint_as_float(u & 0xffff0000u); }

#define SWZ(b) ((b) ^ ((((b) >> 8) & 7) << 4))

struct __align__(16) SmemK1 {
    float rowbuf[32][RBP];
    unsigned h[32 * 64];
    int rmask[32];
    int ords[32];
};

struct __align__(16) SmemK2 {
    float rowbuf[16][RBP];
    unsigned h[16 * 64];
    int rmask[16];
};

__device__ inline void load_rows32(SmemK1& s, const float* __restrict__ src) {
    int t = threadIdx.x;
    for (int idx = t; idx < 32 * 32; idx += NTHREADS) {
        int r = idx >> 5, c4 = (idx & 31) * 4;
        float4 v = *(const float4*)&src[r * DD + c4];
        *(float4*)&s.rowbuf[r][c4] = v;
    }
    __syncthreads();
    for (int idx = t; idx < 32 * 32; idx += NTHREADS) {
        int r = idx >> 5, c4 = (idx & 31) * 4;
        if (s.rmask[r] == 0) *(float4*)&s.rowbuf[r][c4] = make_float4(0.f, 0.f, 0.f, 0.f);
    }
    __syncthreads();
}

__device__ inline void ln32(SmemK1& s, const float* __restrict__ gw,
                            const float* __restrict__ bw,
                            const float* __restrict__ pe_base, bool per_row_pe) {
    int t = threadIdx.x;
    int gr = t >> 3, g = t & 7;
    int base = g * 16;
    float x[16];
    float4* xp = (float4*)x;
    xp[0] = *(const float4*)&s.rowbuf[gr][base + 0];
    xp[1] = *(const float4*)&s.rowbuf[gr][base + 4];
    xp[2] = *(const float4*)&s.rowbuf[gr][base + 8];
    xp[3] = *(const float4*)&s.rowbuf[gr][base + 12];
    float s1 = 0.f, s2 = 0.f;
    #pragma unroll
    for (int i = 0; i < 16; i++) { s1 += x[i]; s2 += x[i] * x[i]; }
    #pragma unroll
    for (int off = 1; off < 8; off <<= 1) {
        s1 += __shfl_xor(s1, off, 64);
        s2 += __shfl_xor(s2, off, 64);
    }
    float mu = s1 * (1.f / 128.f);
    float var = s2 * (1.f / 128.f) - mu * mu;
    float rstd = rsqrtf(var + 1e-5f);
    const float* pe = nullptr;
    if (pe_base) pe = per_row_pe ? (pe_base + (size_t)s.ords[gr] * DD) : pe_base;
    unsigned p[8];
    #pragma unroll
    for (int j = 0; j < 8; j++) {
        int k0 = base + 2 * j;
        float v0 = (x[2 * j] - mu) * rstd * gw[k0] + bw[k0];
        float v1 = (x[2 * j + 1] - mu) * rstd * gw[k0 + 1] + bw[k0 + 1];
        if (pe) { v0 += pe[k0]; v1 += pe[k0 + 1]; }
        p[j] = bf16rne(v0) | (bf16rne(v1) << 16);
    }
    char* hb = (char*)s.h;
    int byte0 = gr * 256 + g * 32;
    uint4 lo = make_uint4(p[0], p[1], p[2], p[3]);
    uint4 hi = make_uint4(p[4], p[5], p[6], p[7]);
    *(uint4*)(hb + SWZ(byte0)) = lo;
    *(uint4*)(hb + SWZ(byte0 + 16)) = hi;
    __syncthreads();
}

template <bool TO_H>
__device__ inline void mm32_f32w(SmemK1& s, const float* __restrict__ Wf,
                                 const float* __restrict__ bias) {
    int t = threadIdx.x;
    int w = t >> 6, l = t & 63;
    int lm = l & 15, lk = l >> 4;
    bf16x8 bfr[2][4];
    #pragma unroll
    for (int nbl = 0; nbl < 2; nbl++) {
        int n = w * 32 + nbl * 16 + lm;
        #pragma unroll
        for (int kb = 0; kb < 4; kb++) {
            int k0 = kb * 32 + lk * 8;
            unsigned pk[4];
            #pragma unroll
            for (int jp = 0; jp < 4; jp++) {
                float a = Wf[(size_t)(k0 + 2 * jp) * DD + n];
                float b = Wf[(size_t)(k0 + 2 * jp + 1) * DD + n];
                pk[jp] = bf16rne(a) | (bf16rne(b) << 16);
            }
            uint4 u = make_uint4(pk[0], pk[1], pk[2], pk[3]);
            bfr[nbl][kb] = *(bf16x8*)&u;
        }
    }
    const char* hb = (const char*)s.h;
    bf16x8 afr[2][4];
    #pragma unroll
    for (int mb = 0; mb < 2; mb++) {
        int row = mb * 16 + lm;
        #pragma unroll
        for (int kb = 0; kb < 4; kb++)
            afr[mb][kb] = *(const bf16x8*)(hb + SWZ(row * 256 + kb * 64 + lk * 16));
    }
    f32x4 acc[2][2];
    #pragma unroll
    for (int mb = 0; mb < 2; mb++)
        #pragma unroll
        for (int nbl = 0; nbl < 2; nbl++)
            acc[mb][nbl] = (f32x4){0.f, 0.f, 0.f, 0.f};
    #pragma unroll
    for (int kb = 0; kb < 4; kb++)
        #pragma unroll
        for (int mb = 0; mb < 2; mb++)
            #pragma unroll
            for (int nbl = 0; nbl < 2; nbl++)
                acc[mb][nbl] = __builtin_amdgcn_mfma_f32_16x16x32_bf16(
                    afr[mb][kb], bfr[nbl][kb], acc[mb][nbl], 0, 0, 0);
    float bcol0 = bias[w * 32 + lm];
    float bcol1 = bias[w * 32 + 16 + lm];
    __syncthreads();
    if (TO_H) {
        char* hw = (char*)s.h;
        #pragma unroll
        for (int mb = 0; mb < 2; mb++)
            #pragma unroll
            for (int nbl = 0; nbl < 2; nbl++) {
                int col = w * 32 + nbl * 16 + lm;
                float bc = nbl ? bcol1 : bcol0;
                #pragma unroll
                for (int j = 0; j < 4; j++) {
                    int row = mb * 16 + lk * 4 + j;
                    float v = fmaxf(acc[mb][nbl][j] + bc, 0.f);
                    *(unsigned short*)(hw + SWZ(row * 256 + col * 2)) =
                        (unsigned short)bf16rne(v);
                }
            }
    } else {
        #pragma unroll
        for (int mb = 0; mb < 2; mb++)
            #pragma unroll
            for (int nbl = 0; nbl < 2; nbl++) {
                int col = w * 32 + nbl * 16 + lm;
                float bc = nbl ? bcol1 : bcol0;
                #pragma unroll
                for (int j = 0; j < 4; j++) {
                    int row = mb * 16 + lk * 4 + j;
                    s.rowbuf[row][col] += acc[mb][nbl][j] + bc;
                }
            }
    }
    __syncthreads();
}

// ---- scan: per-lane nonzero mask + 6-step wave prefix (no serial ballot chain) ----
__device__ inline void scan1(const float* __restrict__ inc,
                             const int* __restrict__ nmask,
                             unsigned* __restrict__ lists, int* __restrict__ cnts,
                             int grow) {
    int l = threadIdx.x & 63;
    if (nmask[grow] == 0) return;
    const float4* ir = (const float4*)(inc + (size_t)grow * EE);
    float4 v[8];
    #pragma unroll
    for (int i = 0; i < 8; i++) v[i] = ir[l + 64 * i];   // 8 KB/wave in flight
    unsigned m = 0;
    #pragma unroll
    for (int i = 0; i < 8; i++) {
        m |= (v[i].x != 0.f ? 1u : 0u) << (4 * i + 0);
        m |= (v[i].y != 0.f ? 1u : 0u) << (4 * i + 1);
        m |= (v[i].z != 0.f ? 1u : 0u) << (4 * i + 2);
        m |= (v[i].w != 0.f ? 1u : 0u) << (4 * i + 3);
    }
    int lc = __popc(m);
    int pre = lc;
    #pragma unroll
    for (int off = 1; off < 64; off <<= 1) {
        int nb = __shfl_up(pre, off, 64);
        if (l >= off) pre += nb;
    }
    int excl = pre - lc;
    unsigned* lp = lists + (size_t)grow * LCAP;
    while (m) {                                  // list order irrelevant: gather sums
        int j = __ffs(m) - 1;
        m &= m - 1;
        if (excl < LCAP) lp[excl] = (unsigned)(4 * (l + 64 * (j >> 2)) + (j & 3));
        excl++;
    }
    if (l == 63) cnts[grow] = pre > LCAP ? LCAP : pre;
}

__device__ inline void ln16(SmemK2& s, const float* __restrict__ gw,
                            const float* __restrict__ bw,
                            const float* __restrict__ pe) {
    int t = threadIdx.x;
    int gr = t >> 4, g = t & 15;
    int base = g * 8;
    float x[8];
    float4* xp = (float4*)x;
    xp[0] = *(const float4*)&s.rowbuf[gr][base + 0];
    xp[1] = *(const float4*)&s.rowbuf[gr][base + 4];
    float s1 = 0.f, s2 = 0.f;
    #pragma unroll
    for (int i = 0; i < 8; i++) { s1 += x[i]; s2 += x[i] * x[i]; }
    #pragma unroll
    for (int off = 1; off < 16; off <<= 1) {
        s1 += __shfl_xor(s1, off, 64);
        s2 += __shfl_xor(s2, off, 64);
    }
    float mu = s1 * (1.f / 128.f);
    float var = s2 * (1.f / 128.f) - mu * mu;
    float rstd = rsqrtf(var + 1e-5f);
    unsigned p[4];
    #pragma unroll
    for (int j = 0; j < 4; j++) {
        int k0 = base + 2 * j;
        float v0 = (x[2 * j] - mu) * rstd * gw[k0] + bw[k0];
        float v1 = (x[2 * j + 1] - mu) * rstd * gw[k0 + 1] + bw[k0 + 1];
        if (pe) { v0 += pe[k0]; v1 += pe[k0 + 1]; }
        p[j] = bf16rne(v0) | (bf16rne(v1) << 16);
    }
    char* hb = (char*)s.h;
    uint4 q = make_uint4(p[0], p[1], p[2], p[3]);
    *(uint4*)(hb + SWZ(gr * 256 + g * 16)) = q;
    __syncthreads();
}

template <bool TO_H>
__device__ inline void mm16(SmemK2& s, const unsigned* __restrict__ WT,
                            const float* __restrict__ bias) {
    int t = threadIdx.x;
    int w = t >> 6, l = t & 63;
    int lm = l & 15, lk = l >> 4;
    bf16x8 bfr[2][4];
    const uint4* wt4 = (const uint4*)WT;
    #pragma unroll
    for (int nbl = 0; nbl < 2; nbl++) {
        int n = w * 32 + nbl * 16 + lm;
        #pragma unroll
        for (int kb = 0; kb < 4; kb++) {
            uint4 u = wt4[n * 16 + kb * 4 + lk];
            bfr[nbl][kb] = *(bf16x8*)&u;
        }
    }
    const char* hb = (const char*)s.h;
    bf16x8 afr[4];
    #pragma unroll
    for (int kb = 0; kb < 4; kb++)
        afr[kb] = *(const bf16x8*)(hb + SWZ(lm * 256 + kb * 64 + lk * 16));
    f32x4 acc[2];
    acc[0] = (f32x4){0.f, 0.f, 0.f, 0.f};
    acc[1] = (f32x4){0.f, 0.f, 0.f, 0.f};
    #pragma unroll
    for (int kb = 0; kb < 4; kb++)
        #pragma unroll
        for (int nbl = 0; nbl < 2; nbl++)
            acc[nbl] = __builtin_amdgcn_mfma_f32_16x16x32_bf16(
                afr[kb], bfr[nbl][kb], acc[nbl], 0, 0, 0);
    float bcol0 = bias[w * 32 + lm];
    float bcol1 = bias[w * 32 + 16 + lm];
    __syncthreads();
    if (TO_H) {
        char* hw = (char*)s.h;
        #pragma unroll
        for (int nbl = 0; nbl < 2; nbl++) {
            int col = w * 32 + nbl * 16 + lm;
            float bc = nbl ? bcol1 : bcol0;
            #pragma unroll
            for (int j = 0; j < 4; j++) {
                int row = lk * 4 + j;
                float v = fmaxf(acc[nbl][j] + bc, 0.f);
                *(unsigned short*)(hw + SWZ(row * 256 + col * 2)) =
                    (unsigned short)bf16rne(v);
            }
        }
    } else {
        #pragma unroll
        for (int nbl = 0; nbl < 2; nbl++) {
            int col = w * 32 + nbl * 16 + lm;
            float bc = nbl ? bcol1 : bcol0;
            #pragma unroll
            for (int j = 0; j < 4; j++) {
                int row = lk * 4 + j;
                s.rowbuf[row][col] += acc[nbl][j] + bc;
            }
        }
    }
    __syncthreads();
}

__device__ inline void gather16(SmemK2& s, int row0,
                                const unsigned* __restrict__ lists,
                                const int* __restrict__ cnts,
                                const unsigned* __restrict__ e2b,
                                const float* __restrict__ sn) {
    int t = threadIdx.x;
    int w = t >> 6, l = t & 63;
    int cnt[4]; unsigned pk[4]; float snv[4];
    #pragma unroll
    for (int i = 0; i < 4; i++) {
        int grow = row0 + w * 4 + i;
        pk[i] = lists[(size_t)grow * LCAP + l];
        snv[i] = sn[grow];
        cnt[i] = cnts[grow];
    }
    #pragma unroll
    for (int i = 0; i < 4; i++) {
        int r = w * 4 + i;
        if (s.rmask[r] == 0) continue;
        int cn = cnt[i]; if (cn > LCAP) cn = LCAP;
        float ax = 0.f, ay = 0.f;
        for (int j0 = 0; j0 < cn; j0 += 8) {
            int nn = cn - j0;
            unsigned uv[8];
            #pragma unroll
            for (int u = 0; u < 8; u++) {
                unsigned e = __shfl(pk[i], j0 + u, 64);
                uv[u] = (u < nn) ? e2b[(size_t)e * 64 + l] : 0u;
            }
            #pragma unroll
            for (int u = 0; u < 8; u++) { ax += bf16lo(uv[u]); ay += bf16hi(uv[u]); }
        }
        float inv = 1.f / (1.f + snv[i]);
        float2* rb = (float2*)&s.rowbuf[r][2 * l];
        float2 cur = *rb;
        cur.x += ax * inv;
        cur.y += ay * inv;
        *rb = cur;
    }
    __syncthreads();
}

__global__ __launch_bounds__(NTHREADS) void k1_kernel(
    const float* __restrict__ x_e, const float* __restrict__ x_v,
    const int* __restrict__ emask, const int* __restrict__ nmask,
    const int* __restrict__ eord, const float* __restrict__ pe1,
    const float* __restrict__ inc,
    const float* __restrict__ n1g, const float* __restrict__ n1b,
    const float* __restrict__ W11, const float* __restrict__ b11,
    const float* __restrict__ W12, const float* __restrict__ b12,
    const float* __restrict__ W21, const float* __restrict__ W22,
    const float* __restrict__ W31, const float* __restrict__ W32,
    unsigned* __restrict__ WT, unsigned* __restrict__ e2pk,
    float* __restrict__ v2out,
    unsigned* __restrict__ lists, int* __restrict__ cnts) {
    int bid = blockIdx.x;
    int t = threadIdx.x;
    if (bid < SCANB) {
        scan1(inc, nmask, lists, cnts, bid * 4 + (t >> 6));
        return;
    }
    __shared__ SmemK1 s;
    int lb = bid - SCANB;
    int gtid = lb * NTHREADS + t;
    if (gtid < 6 * WMAT_U32) {
        int mat = gtid >> 13;
        int idx = gtid & (WMAT_U32 - 1);
        int n = idx >> 6, j = idx & 63;
        const float* W = mat == 0 ? W11 : mat == 1 ? W12 : mat == 2 ? W21
                       : mat == 3 ? W22 : mat == 4 ? W31 : W32;
        float a = W[(2 * j) * DD + n];
        float b = W[(2 * j + 1) * DD + n];
        WT[gtid] = bf16rne(a) | (bf16rne(b) << 16);
    }
    bool isEdge = lb < (BB * EE / 32);
    int mb = isEdge ? lb : lb - (BB * EE / 32);
    int bb = mb & 7;
    int r0 = (mb >> 3) * 32;
    int rowbase = bb * EE + r0;
    const int* mask = isEdge ? emask : nmask;
    if (t < 32) {
        s.rmask[t] = mask[rowbase + t];
        if (isEdge) {
            int o = eord[rowbase + t];
            s.ords[t] = o < 0 ? 0 : (o > 8 ? 8 : o);
        }
    }
    __syncthreads();
    load_rows32(s, (isEdge ? x_e : x_v) + (size_t)rowbase * DD);
    ln32(s, n1g, n1b, isEdge ? pe1 : (pe1 + DD), isEdge);
    mm32_f32w<true>(s, W11, b11);
    mm32_f32w<false>(s, W12, b12);
    if (isEdge) {
        unsigned* dst = e2pk + (size_t)rowbase * (DD / 2);
        for (int idx = t; idx < 32 * 16; idx += NTHREADS) {
            int r = idx >> 4, q = idx & 15;
            uint4 o = make_uint4(0u, 0u, 0u, 0u);
            if (s.rmask[r] != 0) {
                const float* rp = &s.rowbuf[r][q * 8];
                o.x = bf16rne(rp[0]) | (bf16rne(rp[1]) << 16);
                o.y = bf16rne(rp[2]) | (bf16rne(rp[3]) << 16);
                o.z = bf16rne(rp[4]) | (bf16rne(rp[5]) << 16);
                o.w = bf16rne(rp[6]) | (bf16rne(rp[7]) << 16);
            }
            *(uint4*)&dst[r * 64 + q * 4] = o;
        }
    } else {
        for (int idx = t; idx < 32 * 32; idx += NTHREADS) {
            int r = idx >> 5, c4 = (idx & 31) * 4;
            float4 v = make_float4(0.f, 0.f, 0.f, 0.f);
            if (s.rmask[r] != 0) v = *(const float4*)&s.rowbuf[r][c4];
            *(float4*)&v2out[(size_t)(rowbase + r) * DD + c4] = v;
        }
    }
}

__global__ __launch_bounds__(NTHREADS) void k2_kernel(
    const float* __restrict__ v2, const int* __restrict__ nmask,
    const float* __restrict__ sn,
    const float* __restrict__ pe2, const float* __restrict__ biasb,
    const float* __restrict__ n2g, const float* __restrict__ n2b,
    const float* __restrict__ n3g, const float* __restrict__ n3b,
    const unsigned* __restrict__ WT,
    const float* __restrict__ b21, const float* __restrict__ b22,
    const float* __restrict__ b31, const float* __restrict__ b32,
    const unsigned* __restrict__ e2pk, const unsigned* __restrict__ lists,
    const int* __restrict__ cnts, float* __restrict__ out) {
    __shared__ SmemK2 s;
    int bid = blockIdx.x;
    int bb = bid & 7;
    int n0 = (bid >> 3) * 16;
    int row0 = bb * NN + n0;
    int t = threadIdx.x;
    if (t < 16) s.rmask[t] = nmask[row0 + t];
    for (int idx = t; idx < 16 * 32; idx += NTHREADS) {
        int r = idx >> 5, c4 = (idx & 31) * 4;
        float4 v = *(const float4*)&v2[(size_t)(row0 + r) * DD + c4];
        *(float4*)&s.rowbuf[r][c4] = v;
    }
    __syncthreads();
    gather16(s, row0, lists, cnts, e2pk + (size_t)bb * (EE * (DD / 2)), sn);
    ln16(s, n2g, n2b, pe2 + DD);
    mm16<true>(s, WT + 2 * WMAT_U32, b21);
    mm16<false>(s, WT + 3 * WMAT_U32, b22);
    ln16(s, n3g, n3b, nullptr);
    mm16<true>(s, WT + 4 * WMAT_U32, b31);
    mm16<false>(s, WT + 5 * WMAT_U32, b32);
    for (int idx = t; idx < 16 * 32; idx += NTHREADS) {
        int r = idx >> 5, c4 = (idx & 31) * 4;
        float4 v = make_float4(0.f, 0.f, 0.f, 0.f);
        if (s.rmask[r] != 0) {
            v = *(const float4*)&s.rowbuf[r][c4];
            float4 bbv = *(const float4*)&biasb[c4];
            v.x += bbv.x; v.y += bbv.y; v.z += bbv.z; v.w += bbv.w;
        }
        *(float4*)&out[(size_t)(row0 + r) * DD + c4] = v;
    }
}

extern "C" void kernel_launch(void* const* d_in, const int* in_sizes, int n_in,
                              void* d_out, int out_size, void* d_ws, size_t ws_size,
                              hipStream_t stream) {
    const float* x_v   = (const float*)d_in[0];
    const float* x_e   = (const float*)d_in[1];
    const float* inc   = (const float*)d_in[2];
    const float* sn    = (const float*)d_in[3];
    const int*   eord  = (const int*)d_in[4];
    const int*   nmask = (const int*)d_in[5];
    const int*   emask = (const int*)d_in[6];
    const float* pe1   = (const float*)d_in[7];
    const float* pe2   = (const float*)d_in[8];
    const float* biasb = (const float*)d_in[9];
    const float* W11   = (const float*)d_in[10];
    const float* b11   = (const float*)d_in[11];
    const float* W12   = (const float*)d_in[12];
    const float* b12   = (const float*)d_in[13];
    const float* W21   = (const float*)d_in[14];
    const float* b21   = (const float*)d_in[15];
    const float* W22   = (const float*)d_in[16];
    const float* b22   = (const float*)d_in[17];
    const float* W31   = (const float*)d_in[18];
    const float* b31   = (const float*)d_in[19];
    const float* W32   = (const float*)d_in[20];
    const float* b32   = (const float*)d_in[21];
    const float* n1g   = (const float*)d_in[22];
    const float* n1b   = (const float*)d_in[23];
    const float* n2g   = (const float*)d_in[24];
    const float* n2b   = (const float*)d_in[25];
    const float* n3g   = (const float*)d_in[26];
    const float* n3b   = (const float*)d_in[27];

    unsigned* e2pk  = (unsigned*)d_ws;
    unsigned* WT    = e2pk + (size_t)BB * EE * (DD / 2);
    unsigned* lists = WT + 6 * WMAT_U32;
    int*      cnts  = (int*)(lists + (size_t)BB * NN * LCAP);
    float*    out   = (float*)d_out;

    dim3 blk(NTHREADS);
    k1_kernel<<<dim3(SCANB + MLPB), blk, 0, stream>>>(
        x_e, x_v, emask, nmask, eord, pe1, inc,
        n1g, n1b, W11, b11, W12, b12, W21, W22, W31, W32,
        WT, e2pk, out, lists, cnts);
    k2_kernel<<<dim3(BB * NN / 16), blk, 0, stream>>>(
        out, nmask, sn, pe2, biasb,
        n2g, n2b, n3g, n3b,
        WT, b21, b22, b31, b32,
        e2pk, lists, cnts, out);
}

// Round 21
// 61.395 us; speedup vs baseline: 1.4091x; 1.0084x over previous
//
#include <hip/hip_runtime.h>
#include <stdint.h>

#define BB 8
#define NN 2048
#define EE 2048
#define DD 128
#define RBP 132
#define NTHREADS 256
#define WMAT_U32 8192
#define SCANB 4096
#define MLPB 1024
#define LCAP 64

typedef __attribute__((ext_vector_type(8))) short bf16x8;
typedef __attribute__((ext_vector_type(4))) float f32x4;

__device__ inline unsigned bf16rne(float f) {
    unsigned u = __float_as_uint(f);
    return (u + 0x7fffu + ((u >> 16) & 1u)) >> 16;
}
__device__ inline float bf16lo(unsigned u) { return __uint_as_float(u << 16); }
__device__ inline float bf16hi(unsigned u) { return __uint_as_float(u & 0xffff0000u); }

#define SWZ(b) ((b) ^ ((((b) >> 8) & 7) << 4))

struct __align__(16) SmemK1 {
    float rowbuf[32][RBP];
    unsigned h[32 * 64];
    int rmask[32];
    int ords[32];
};

struct __align__(16) SmemK2 {
    float rowbuf[16][RBP];
    unsigned h[16 * 64];
    int rmask[16];
};

__device__ inline void load_rows32(SmemK1& s, const float* __restrict__ src) {
    int t = threadIdx.x;
    for (int idx = t; idx < 32 * 32; idx += NTHREADS) {
        int r = idx >> 5, c4 = (idx & 31) * 4;
        // single-use stream: bypass L2 (nt load needs ext_vector type)
        f32x4 v = __builtin_nontemporal_load((const f32x4*)&src[r * DD + c4]);
        *(f32x4*)&s.rowbuf[r][c4] = v;
    }
    __syncthreads();
    for (int idx = t; idx < 32 * 32; idx += NTHREADS) {
        int r = idx >> 5, c4 = (idx & 31) * 4;
        if (s.rmask[r] == 0) *(f32x4*)&s.rowbuf[r][c4] = (f32x4){0.f, 0.f, 0.f, 0.f};
    }
    __syncthreads();
}

__device__ inline void ln32(SmemK1& s, const float* __restrict__ gw,
                            const float* __restrict__ bw,
                            const float* __restrict__ pe_base, bool per_row_pe) {
    int t = threadIdx.x;
    int gr = t >> 3, g = t & 7;
    int base = g * 16;
    float x[16];
    float4* xp = (float4*)x;
    xp[0] = *(const float4*)&s.rowbuf[gr][base + 0];
    xp[1] = *(const float4*)&s.rowbuf[gr][base + 4];
    xp[2] = *(const float4*)&s.rowbuf[gr][base + 8];
    xp[3] = *(const float4*)&s.rowbuf[gr][base + 12];
    float s1 = 0.f, s2 = 0.f;
    #pragma unroll
    for (int i = 0; i < 16; i++) { s1 += x[i]; s2 += x[i] * x[i]; }
    #pragma unroll
    for (int off = 1; off < 8; off <<= 1) {
        s1 += __shfl_xor(s1, off, 64);
        s2 += __shfl_xor(s2, off, 64);
    }
    float mu = s1 * (1.f / 128.f);
    float var = s2 * (1.f / 128.f) - mu * mu;
    float rstd = rsqrtf(var + 1e-5f);
    const float* pe = nullptr;
    if (pe_base) pe = per_row_pe ? (pe_base + (size_t)s.ords[gr] * DD) : pe_base;
    unsigned p[8];
    #pragma unroll
    for (int j = 0; j < 8; j++) {
        int k0 = base + 2 * j;
        float v0 = (x[2 * j] - mu) * rstd * gw[k0] + bw[k0];
        float v1 = (x[2 * j + 1] - mu) * rstd * gw[k0 + 1] + bw[k0 + 1];
        if (pe) { v0 += pe[k0]; v1 += pe[k0 + 1]; }
        p[j] = bf16rne(v0) | (bf16rne(v1) << 16);
    }
    char* hb = (char*)s.h;
    int byte0 = gr * 256 + g * 32;
    uint4 lo = make_uint4(p[0], p[1], p[2], p[3]);
    uint4 hi = make_uint4(p[4], p[5], p[6], p[7]);
    *(uint4*)(hb + SWZ(byte0)) = lo;
    *(uint4*)(hb + SWZ(byte0 + 16)) = hi;
    __syncthreads();
}

template <bool TO_H>
__device__ inline void mm32_f32w(SmemK1& s, const float* __restrict__ Wf,
                                 const float* __restrict__ bias) {
    int t = threadIdx.x;
    int w = t >> 6, l = t & 63;
    int lm = l & 15, lk = l >> 4;
    bf16x8 bfr[2][4];
    #pragma unroll
    for (int nbl = 0; nbl < 2; nbl++) {
        int n = w * 32 + nbl * 16 + lm;
        #pragma unroll
        for (int kb = 0; kb < 4; kb++) {
            int k0 = kb * 32 + lk * 8;
            unsigned pk[4];
            #pragma unroll
            for (int jp = 0; jp < 4; jp++) {
                float a = Wf[(size_t)(k0 + 2 * jp) * DD + n];
                float b = Wf[(size_t)(k0 + 2 * jp + 1) * DD + n];
                pk[jp] = bf16rne(a) | (bf16rne(b) << 16);
            }
            uint4 u = make_uint4(pk[0], pk[1], pk[2], pk[3]);
            bfr[nbl][kb] = *(bf16x8*)&u;
        }
    }
    const char* hb = (const char*)s.h;
    bf16x8 afr[2][4];
    #pragma unroll
    for (int mb = 0; mb < 2; mb++) {
        int row = mb * 16 + lm;
        #pragma unroll
        for (int kb = 0; kb < 4; kb++)
            afr[mb][kb] = *(const bf16x8*)(hb + SWZ(row * 256 + kb * 64 + lk * 16));
    }
    f32x4 acc[2][2];
    #pragma unroll
    for (int mb = 0; mb < 2; mb++)
        #pragma unroll
        for (int nbl = 0; nbl < 2; nbl++)
            acc[mb][nbl] = (f32x4){0.f, 0.f, 0.f, 0.f};
    #pragma unroll
    for (int kb = 0; kb < 4; kb++)
        #pragma unroll
        for (int mb = 0; mb < 2; mb++)
            #pragma unroll
            for (int nbl = 0; nbl < 2; nbl++)
                acc[mb][nbl] = __builtin_amdgcn_mfma_f32_16x16x32_bf16(
                    afr[mb][kb], bfr[nbl][kb], acc[mb][nbl], 0, 0, 0);
    float bcol0 = bias[w * 32 + lm];
    float bcol1 = bias[w * 32 + 16 + lm];
    __syncthreads();
    if (TO_H) {
        char* hw = (char*)s.h;
        #pragma unroll
        for (int mb = 0; mb < 2; mb++)
            #pragma unroll
            for (int nbl = 0; nbl < 2; nbl++) {
                int col = w * 32 + nbl * 16 + lm;
                float bc = nbl ? bcol1 : bcol0;
                #pragma unroll
                for (int j = 0; j < 4; j++) {
                    int row = mb * 16 + lk * 4 + j;
                    float v = fmaxf(acc[mb][nbl][j] + bc, 0.f);
                    *(unsigned short*)(hw + SWZ(row * 256 + col * 2)) =
                        (unsigned short)bf16rne(v);
                }
            }
    } else {
        #pragma unroll
        for (int mb = 0; mb < 2; mb++)
            #pragma unroll
            for (int nbl = 0; nbl < 2; nbl++) {
                int col = w * 32 + nbl * 16 + lm;
                float bc = nbl ? bcol1 : bcol0;
                #pragma unroll
                for (int j = 0; j < 4; j++) {
                    int row = mb * 16 + lk * 4 + j;
                    s.rowbuf[row][col] += acc[mb][nbl][j] + bc;
                }
            }
    }
    __syncthreads();
}

// ---- scan: per-lane nonzero mask + 6-step wave prefix; NT loads bypass L2 ----
__device__ inline void scan1(const float* __restrict__ inc,
                             const int* __restrict__ nmask,
                             unsigned* __restrict__ lists, int* __restrict__ cnts,
                             int grow) {
    int l = threadIdx.x & 63;
    if (nmask[grow] == 0) return;
    const f32x4* ir = (const f32x4*)(inc + (size_t)grow * EE);
    f32x4 v[8];
    #pragma unroll
    for (int i = 0; i < 8; i++)
        v[i] = __builtin_nontemporal_load(&ir[l + 64 * i]);   // 8 KB/wave, no L2 install
    unsigned m = 0;
    #pragma unroll
    for (int i = 0; i < 8; i++) {
        m |= (v[i][0] != 0.f ? 1u : 0u) << (4 * i + 0);
        m |= (v[i][1] != 0.f ? 1u : 0u) << (4 * i + 1);
        m |= (v[i][2] != 0.f ? 1u : 0u) << (4 * i + 2);
        m |= (v[i][3] != 0.f ? 1u : 0u) << (4 * i + 3);
    }
    int lc = __popc(m);
    int pre = lc;
    #pragma unroll
    for (int off = 1; off < 64; off <<= 1) {
        int nb = __shfl_up(pre, off, 64);
        if (l >= off) pre += nb;
    }
    int excl = pre - lc;
    unsigned* lp = lists + (size_t)grow * LCAP;
    while (m) {                                  // list order irrelevant: gather sums
        int j = __ffs(m) - 1;
        m &= m - 1;
        if (excl < LCAP) lp[excl] = (unsigned)(4 * (l + 64 * (j >> 2)) + (j & 3));
        excl++;
    }
    if (l == 63) cnts[grow] = pre > LCAP ? LCAP : pre;
}

__device__ inline void ln16(SmemK2& s, const float* __restrict__ gw,
                            const float* __restrict__ bw,
                            const float* __restrict__ pe) {
    int t = threadIdx.x;
    int gr = t >> 4, g = t & 15;
    int base = g * 8;
    float x[8];
    float4* xp = (float4*)x;
    xp[0] = *(const float4*)&s.rowbuf[gr][base + 0];
    xp[1] = *(const float4*)&s.rowbuf[gr][base + 4];
    float s1 = 0.f, s2 = 0.f;
    #pragma unroll
    for (int i = 0; i < 8; i++) { s1 += x[i]; s2 += x[i] * x[i]; }
    #pragma unroll
    for (int off = 1; off < 16; off <<= 1) {
        s1 += __shfl_xor(s1, off, 64);
        s2 += __shfl_xor(s2, off, 64);
    }
    float mu = s1 * (1.f / 128.f);
    float var = s2 * (1.f / 128.f) - mu * mu;
    float rstd = rsqrtf(var + 1e-5f);
    unsigned p[4];
    #pragma unroll
    for (int j = 0; j < 4; j++) {
        int k0 = base + 2 * j;
        float v0 = (x[2 * j] - mu) * rstd * gw[k0] + bw[k0];
        float v1 = (x[2 * j + 1] - mu) * rstd * gw[k0 + 1] + bw[k0 + 1];
        if (pe) { v0 += pe[k0]; v1 += pe[k0 + 1]; }
        p[j] = bf16rne(v0) | (bf16rne(v1) << 16);
    }
    char* hb = (char*)s.h;
    uint4 q = make_uint4(p[0], p[1], p[2], p[3]);
    *(uint4*)(hb + SWZ(gr * 256 + g * 16)) = q;
    __syncthreads();
}

template <bool TO_H>
__device__ inline void mm16(SmemK2& s, const unsigned* __restrict__ WT,
                            const float* __restrict__ bias) {
    int t = threadIdx.x;
    int w = t >> 6, l = t & 63;
    int lm = l & 15, lk = l >> 4;
    bf16x8 bfr[2][4];
    const uint4* wt4 = (const uint4*)WT;
    #pragma unroll
    for (int nbl = 0; nbl < 2; nbl++) {
        int n = w * 32 + nbl * 16 + lm;
        #pragma unroll
        for (int kb = 0; kb < 4; kb++) {
            uint4 u = wt4[n * 16 + kb * 4 + lk];
            bfr[nbl][kb] = *(bf16x8*)&u;
        }
    }
    const char* hb = (const char*)s.h;
    bf16x8 afr[4];
    #pragma unroll
    for (int kb = 0; kb < 4; kb++)
        afr[kb] = *(const bf16x8*)(hb + SWZ(lm * 256 + kb * 64 + lk * 16));
    f32x4 acc[2];
    acc[0] = (f32x4){0.f, 0.f, 0.f, 0.f};
    acc[1] = (f32x4){0.f, 0.f, 0.f, 0.f};
    #pragma unroll
    for (int kb = 0; kb < 4; kb++)
        #pragma unroll
        for (int nbl = 0; nbl < 2; nbl++)
            acc[nbl] = __builtin_amdgcn_mfma_f32_16x16x32_bf16(
                afr[kb], bfr[nbl][kb], acc[nbl], 0, 0, 0);
    float bcol0 = bias[w * 32 + lm];
    float bcol1 = bias[w * 32 + 16 + lm];
    __syncthreads();
    if (TO_H) {
        char* hw = (char*)s.h;
        #pragma unroll
        for (int nbl = 0; nbl < 2; nbl++) {
            int col = w * 32 + nbl * 16 + lm;
            float bc = nbl ? bcol1 : bcol0;
            #pragma unroll
            for (int j = 0; j < 4; j++) {
                int row = lk * 4 + j;
                float v = fmaxf(acc[nbl][j] + bc, 0.f);
                *(unsigned short*)(hw + SWZ(row * 256 + col * 2)) =
                    (unsigned short)bf16rne(v);
            }
        }
    } else {
        #pragma unroll
        for (int nbl = 0; nbl < 2; nbl++) {
            int col = w * 32 + nbl * 16 + lm;
            float bc = nbl ? bcol1 : bcol0;
            #pragma unroll
            for (int j = 0; j < 4; j++) {
                int row = lk * 4 + j;
                s.rowbuf[row][col] += acc[nbl][j] + bc;
            }
        }
    }
    __syncthreads();
}

__device__ inline void gather16(SmemK2& s, int row0,
                                const unsigned* __restrict__ lists,
                                const int* __restrict__ cnts,
                                const unsigned* __restrict__ e2b,
                                const float* __restrict__ sn) {
    int t = threadIdx.x;
    int w = t >> 6, l = t & 63;
    int cnt[4]; unsigned pk[4]; float snv[4];
    #pragma unroll
    for (int i = 0; i < 4; i++) {
        int grow = row0 + w * 4 + i;
        pk[i] = lists[(size_t)grow * LCAP + l];
        snv[i] = sn[grow];
        cnt[i] = cnts[grow];
    }
    #pragma unroll
    for (int i = 0; i < 4; i++) {
        int r = w * 4 + i;
        if (s.rmask[r] == 0) continue;
        int cn = cnt[i]; if (cn > LCAP) cn = LCAP;
        float ax = 0.f, ay = 0.f;
        for (int j0 = 0; j0 < cn; j0 += 8) {
            int nn = cn - j0;
            unsigned uv[8];
            #pragma unroll
            for (int u = 0; u < 8; u++) {
                unsigned e = __shfl(pk[i], j0 + u, 64);
                uv[u] = (u < nn) ? e2b[(size_t)e * 64 + l] : 0u;
            }
            #pragma unroll
            for (int u = 0; u < 8; u++) { ax += bf16lo(uv[u]); ay += bf16hi(uv[u]); }
        }
        float inv = 1.f / (1.f + snv[i]);
        float2* rb = (float2*)&s.rowbuf[r][2 * l];
        float2 cur = *rb;
        cur.x += ax * inv;
        cur.y += ay * inv;
        *rb = cur;
    }
    __syncthreads();
}

__global__ __launch_bounds__(NTHREADS) void k1_kernel(
    const float* __restrict__ x_e, const float* __restrict__ x_v,
    const int* __restrict__ emask, const int* __restrict__ nmask,
    const int* __restrict__ eord, const float* __restrict__ pe1,
    const float* __restrict__ inc,
    const float* __restrict__ n1g, const float* __restrict__ n1b,
    const float* __restrict__ W11, const float* __restrict__ b11,
    const float* __restrict__ W12, const float* __restrict__ b12,
    const float* __restrict__ W21, const float* __restrict__ W22,
    const float* __restrict__ W31, const float* __restrict__ W32,
    unsigned* __restrict__ WT, unsigned* __restrict__ e2pk,
    float* __restrict__ v2out,
    unsigned* __restrict__ lists, int* __restrict__ cnts) {
    int bid = blockIdx.x;
    int t = threadIdx.x;
    if (bid < SCANB) {
        scan1(inc, nmask, lists, cnts, bid * 4 + (t >> 6));
        return;
    }
    __shared__ SmemK1 s;
    int lb = bid - SCANB;
    int gtid = lb * NTHREADS + t;
    if (gtid < 6 * WMAT_U32) {
        int mat = gtid >> 13;
        int idx = gtid & (WMAT_U32 - 1);
        int n = idx >> 6, j = idx & 63;
        const float* W = mat == 0 ? W11 : mat == 1 ? W12 : mat == 2 ? W21
                       : mat == 3 ? W22 : mat == 4 ? W31 : W32;
        float a = W[(2 * j) * DD + n];
        float b = W[(2 * j + 1) * DD + n];
        WT[gtid] = bf16rne(a) | (bf16rne(b) << 16);
    }
    bool isEdge = lb < (BB * EE / 32);
    int mb = isEdge ? lb : lb - (BB * EE / 32);
    int bb = mb & 7;
    int r0 = (mb >> 3) * 32;
    int rowbase = bb * EE + r0;
    const int* mask = isEdge ? emask : nmask;
    if (t < 32) {
        s.rmask[t] = mask[rowbase + t];
        if (isEdge) {
            int o = eord[rowbase + t];
            s.ords[t] = o < 0 ? 0 : (o > 8 ? 8 : o);
        }
    }
    __syncthreads();
    load_rows32(s, (isEdge ? x_e : x_v) + (size_t)rowbase * DD);
    ln32(s, n1g, n1b, isEdge ? pe1 : (pe1 + DD), isEdge);
    mm32_f32w<true>(s, W11, b11);
    mm32_f32w<false>(s, W12, b12);
    if (isEdge) {
        unsigned* dst = e2pk + (size_t)rowbase * (DD / 2);
        for (int idx = t; idx < 32 * 16; idx += NTHREADS) {
            int r = idx >> 4, q = idx & 15;
            uint4 o = make_uint4(0u, 0u, 0u, 0u);
            if (s.rmask[r] != 0) {
                const float* rp = &s.rowbuf[r][q * 8];
                o.x = bf16rne(rp[0]) | (bf16rne(rp[1]) << 16);
                o.y = bf16rne(rp[2]) | (bf16rne(rp[3]) << 16);
                o.z = bf16rne(rp[4]) | (bf16rne(rp[5]) << 16);
                o.w = bf16rne(rp[6]) | (bf16rne(rp[7]) << 16);
            }
            *(uint4*)&dst[r * 64 + q * 4] = o;   // keep in L2: K2 reads it
        }
    } else {
        for (int idx = t; idx < 32 * 32; idx += NTHREADS) {
            int r = idx >> 5, c4 = (idx & 31) * 4;
            float4 v = make_float4(0.f, 0.f, 0.f, 0.f);
            if (s.rmask[r] != 0) v = *(const float4*)&s.rowbuf[r][c4];
            *(float4*)&v2out[(size_t)(rowbase + r) * DD + c4] = v;   // keep in L2
        }
    }
}

__global__ __launch_bounds__(NTHREADS) void k2_kernel(
    const float* __restrict__ v2, const int* __restrict__ nmask,
    const float* __restrict__ sn,
    const float* __restrict__ pe2, const float* __restrict__ biasb,
    const float* __restrict__ n2g, const float* __restrict__ n2b,
    const float* __restrict__ n3g, const float* __restrict__ n3b,
    const unsigned* __restrict__ WT,
    const float* __restrict__ b21, const float* __restrict__ b22,
    const float* __restrict__ b31, const float* __restrict__ b32,
    const unsigned* __restrict__ e2pk, const unsigned* __restrict__ lists,
    const int* __restrict__ cnts, float* __restrict__ out) {
    __shared__ SmemK2 s;
    int bid = blockIdx.x;
    int bb = bid & 7;
    int n0 = (bid >> 3) * 16;
    int row0 = bb * NN + n0;
    int t = threadIdx.x;
    if (t < 16) s.rmask[t] = nmask[row0 + t];
    for (int idx = t; idx < 16 * 32; idx += NTHREADS) {
        int r = idx >> 5, c4 = (idx & 31) * 4;
        float4 v = *(const float4*)&v2[(size_t)(row0 + r) * DD + c4];
        *(float4*)&s.rowbuf[r][c4] = v;
    }
    __syncthreads();
    gather16(s, row0, lists, cnts, e2pk + (size_t)bb * (EE * (DD / 2)), sn);
    ln16(s, n2g, n2b, pe2 + DD);
    mm16<true>(s, WT + 2 * WMAT_U32, b21);
    mm16<false>(s, WT + 3 * WMAT_U32, b22);
    ln16(s, n3g, n3b, nullptr);
    mm16<true>(s, WT + 4 * WMAT_U32, b31);
    mm16<false>(s, WT + 5 * WMAT_U32, b32);
    for (int idx = t; idx < 16 * 32; idx += NTHREADS) {
        int r = idx >> 5, c4 = (idx & 31) * 4;
        f32x4 v = (f32x4){0.f, 0.f, 0.f, 0.f};
        if (s.rmask[r] != 0) {
            f32x4 cur = *(const f32x4*)&s.rowbuf[r][c4];
            f32x4 bbv = *(const f32x4*)&biasb[c4];
            v = cur + bbv;
        }
        // final output: never re-read on device -> bypass L2
        __builtin_nontemporal_store(v, (f32x4*)&out[(size_t)(row0 + r) * DD + c4]);
    }
}

extern "C" void kernel_launch(void* const* d_in, const int* in_sizes, int n_in,
                              void* d_out, int out_size, void* d_ws, size_t ws_size,
                              hipStream_t stream) {
    const float* x_v   = (const float*)d_in[0];
    const float* x_e   = (const float*)d_in[1];
    const float* inc   = (const float*)d_in[2];
    const float* sn    = (const float*)d_in[3];
    const int*   eord  = (const int*)d_in[4];
    const int*   nmask = (const int*)d_in[5];
    const int*   emask = (const int*)d_in[6];
    const float* pe1   = (const float*)d_in[7];
    const float* pe2   = (const float*)d_in[8];
    const float* biasb = (const float*)d_in[9];
    const float* W11   = (const float*)d_in[10];
    const float* b11   = (const float*)d_in[11];
    const float* W12   = (const float*)d_in[12];
    const float* b12   = (const float*)d_in[13];
    const float* W21   = (const float*)d_in[14];
    const float* b21   = (const float*)d_in[15];
    const float* W22   = (const float*)d_in[16];
    const float* b22   = (const float*)d_in[17];
    const float* W31   = (const float*)d_in[18];
    const float* b31   = (const float*)d_in[19];
    const float* W32   = (const float*)d_in[20];
    const float* b32   = (const float*)d_in[21];
    const float* n1g   = (const float*)d_in[22];
    const float* n1b   = (const float*)d_in[23];
    const float* n2g   = (const float*)d_in[24];
    const float* n2b   = (const float*)d_in[25];
    const float* n3g   = (const float*)d_in[26];
    const float* n3b   = (const float*)d_in[27];

    unsigned* e2pk  = (unsigned*)d_ws;
    unsigned* WT    = e2pk + (size_t)BB * EE * (DD / 2);
    unsigned* lists = WT + 6 * WMAT_U32;
    int*      cnts  = (int*)(lists + (size_t)BB * NN * LCAP);
    float*    out   = (float*)d_out;

    dim3 blk(NTHREADS);
    k1_kernel<<<dim3(SCANB + MLPB), blk, 0, stream>>>(
        x_e, x_v, emask, nmask, eord, pe1, inc,
        n1g, n1b, W11, b11, W12, b12, W21, W22, W31, W32,
        WT, e2pk, out, lists, cnts);
    k2_kernel<<<dim3(BB * NN / 16), blk, 0, stream>>>(
        out, nmask, sn, pe2, biasb,
        n2g, n2b, n3g, n3b,
        WT, b21, b22, b31, b32,
        e2pk, lists, cnts, out);
}